// Round 1
// baseline (1446.109 us; speedup 1.0000x reference)
//
#include <hip/hip_runtime.h>
#include <math.h>

#define Bb 8
#define Cc 64
#define Hh 256
#define Ww 256
#define HID 8
#define PLANE (Hh*Ww)

// Kernel A: theta = pi*sigmoid(conv1x1(relu(conv3x3(x)))) -> cos/sin maps
__global__ __launch_bounds__(256) void theta_kernel(
    const float* __restrict__ x, const float* __restrict__ w3,
    const float* __restrict__ b3, const float* __restrict__ w1,
    const float* __restrict__ b1, float* __restrict__ cosout,
    float* __restrict__ sinout)
{
    const int tx = threadIdx.x & 63;
    const int ty = threadIdx.x >> 6;
    const int xx = blockIdx.x * 64 + tx;
    const int yy = blockIdx.y * 4 + ty;
    const int b  = blockIdx.z;

    const int ym = yy - 1, yp = yy + 1;
    const int xm = xx - 1, xp = xx + 1;
    const bool vym = (ym >= 0), vyp = (yp < Hh);
    const bool vxm = (xm >= 0), vxp = (xp < Ww);
    const int ymc = vym ? ym : 0, ypc = vyp ? yp : (Hh - 1);
    const int xmc = vxm ? xm : 0, xpc = vxp ? xp : (Ww - 1);

    const float* xb = x + (size_t)b * Cc * PLANE;

    float acc[HID];
    #pragma unroll
    for (int h = 0; h < HID; h++) acc[h] = 0.f;

    for (int c = 0; c < Cc; c++) {
        const float* xc = xb + c * PLANE;
        float v[9];
        v[0] = (vym && vxm) ? xc[ymc * Ww + xmc] : 0.f;
        v[1] = (vym)        ? xc[ymc * Ww + xx ] : 0.f;
        v[2] = (vym && vxp) ? xc[ymc * Ww + xpc] : 0.f;
        v[3] = (vxm)        ? xc[yy  * Ww + xmc] : 0.f;
        v[4] =                xc[yy  * Ww + xx ];
        v[5] = (vxp)        ? xc[yy  * Ww + xpc] : 0.f;
        v[6] = (vyp && vxm) ? xc[ypc * Ww + xmc] : 0.f;
        v[7] = (vyp)        ? xc[ypc * Ww + xx ] : 0.f;
        v[8] = (vyp && vxp) ? xc[ypc * Ww + xpc] : 0.f;
        #pragma unroll
        for (int h = 0; h < HID; h++) {
            const float* wk = w3 + (h * Cc + c) * 9;  // uniform -> s_load
            float a = acc[h];
            #pragma unroll
            for (int k = 0; k < 9; k++) a = fmaf(wk[k], v[k], a);
            acc[h] = a;
        }
    }

    float z = b1[0];
    #pragma unroll
    for (int h = 0; h < HID; h++) {
        float hr = acc[h] + b3[h];
        hr = hr > 0.f ? hr : 0.f;
        z = fmaf(w1[h], hr, z);
    }
    const float theta = 3.14159265358979f / (1.f + __expf(-z));
    float s, co;
    __sincosf(theta, &s, &co);
    const int p = b * PLANE + yy * Ww + xx;
    cosout[p] = co;
    sinout[p] = s;
}

// Kernel B: oriented pooling fused with 128->8->128 attention convs + output.
// Context is never materialized: each channel's pooled (tan, nor) pair is
// reduced immediately into the 8 hidden accumulators.
__global__ __launch_bounds__(256) void pool_kernel(
    const float* __restrict__ x,
    const float* __restrict__ cosb, const float* __restrict__ sinb,
    const float* __restrict__ wr, const float* __restrict__ br,
    const float* __restrict__ we, const float* __restrict__ be,
    float* __restrict__ out)
{
    const int tx = threadIdx.x & 63;
    const int ty = threadIdx.x >> 6;
    const int xx = blockIdx.x * 64 + tx;
    const int yy = blockIdx.y * 4 + ty;
    const int b  = blockIdx.z;
    const int p  = b * PLANE + yy * Ww + xx;

    const float vx = cosb[p];   // cos(theta)
    const float vy = sinb[p];   // sin(theta)

    // Precompute 18 bilinear sample descriptors (9 tan + 9 nor).
    // Clamp trick: x0=min(floor(cx),W-2), wx=cx-x0 reproduces reference edge
    // behavior exactly and keeps addr/addr+1/addr+W/addr+W+1 in-bounds.
    int   off[18];
    float fwy[18], fwx[18];
    #pragma unroll
    for (int s = 0; s < 9; s++) {
        const float t = (float)(s - 4);
        // tangential: (vx, vy) = (cos, sin): cy = y + t*sin, cx = x + t*cos
        float cy = fminf(fmaxf((float)yy + t * vy, 0.f), (float)(Hh - 1));
        float cx = fminf(fmaxf((float)xx + t * vx, 0.f), (float)(Ww - 1));
        int y0 = min((int)cy, Hh - 2);
        int x0 = min((int)cx, Ww - 2);
        off[s] = y0 * Ww + x0;
        fwy[s] = cy - (float)y0;
        fwx[s] = cx - (float)x0;
        // normal: (vx, vy) = (-sin, cos): cy = y + t*cos, cx = x - t*sin
        float cy2 = fminf(fmaxf((float)yy + t * vx, 0.f), (float)(Hh - 1));
        float cx2 = fminf(fmaxf((float)xx - t * vy, 0.f), (float)(Ww - 1));
        int y02 = min((int)cy2, Hh - 2);
        int x02 = min((int)cx2, Ww - 2);
        off[9 + s] = y02 * Ww + x02;
        fwy[9 + s] = cy2 - (float)y02;
        fwx[9 + s] = cx2 - (float)x02;
    }

    float hid[HID];
    #pragma unroll
    for (int h = 0; h < HID; h++) hid[h] = br[h];

    const float* xb = x + (size_t)b * Cc * PLANE;

    for (int c = 0; c < Cc; c++) {
        const float* xc = xb + c * PLANE;
        float tacc = 0.f, nacc = 0.f;
        #pragma unroll
        for (int s = 0; s < 18; s++) {
            const int o = off[s];
            const float v00 = xc[o];
            const float v01 = xc[o + 1];
            const float v10 = xc[o + Ww];
            const float v11 = xc[o + Ww + 1];
            const float wx_ = fwx[s], wy_ = fwy[s];
            const float top = v00 + wx_ * (v01 - v00);
            const float bot = v10 + wx_ * (v11 - v10);
            const float val = top + wy_ * (bot - top);
            if (s < 9) tacc += val; else nacc += val;
        }
        tacc *= (1.f / 9.f);
        nacc *= (1.f / 9.f);
        #pragma unroll
        for (int h = 0; h < HID; h++) {
            hid[h] = fmaf(wr[h * 128 + c],      tacc, hid[h]);  // uniform -> s_load
            hid[h] = fmaf(wr[h * 128 + 64 + c], nacc, hid[h]);
        }
    }

    #pragma unroll
    for (int h = 0; h < HID; h++) hid[h] = fmaxf(hid[h], 0.f);

    // Epilogue: w = sigmoid(we @ hidden + be); out = (w[c] + w[c+64]) * x[c]
    const int pix = yy * Ww + xx;
    for (int c = 0; c < Cc; c++) {
        float z1 = be[c];
        float z2 = be[c + 64];
        #pragma unroll
        for (int h = 0; h < HID; h++) {
            z1 = fmaf(we[c * 8 + h],        hid[h], z1);
            z2 = fmaf(we[(c + 64) * 8 + h], hid[h], z2);
        }
        const float a1 = 1.f / (1.f + __expf(-z1));
        const float a2 = 1.f / (1.f + __expf(-z2));
        const float xv = xb[c * PLANE + pix];
        out[(size_t)(b * Cc + c) * PLANE + pix] = (a1 + a2) * xv;
    }
}

extern "C" void kernel_launch(void* const* d_in, const int* in_sizes, int n_in,
                              void* d_out, int out_size, void* d_ws, size_t ws_size,
                              hipStream_t stream) {
    const float* x  = (const float*)d_in[0];
    const float* w3 = (const float*)d_in[1];
    const float* b3 = (const float*)d_in[2];
    const float* w1 = (const float*)d_in[3];
    const float* b1 = (const float*)d_in[4];
    const float* wr = (const float*)d_in[5];
    const float* br = (const float*)d_in[6];
    const float* we = (const float*)d_in[7];
    const float* be = (const float*)d_in[8];
    float* out = (float*)d_out;

    float* cosb = (float*)d_ws;                    // B*H*W floats
    float* sinb = cosb + (size_t)Bb * PLANE;       // B*H*W floats

    dim3 grid(Ww / 64, Hh / 4, Bb);
    dim3 block(256);
    theta_kernel<<<grid, block, 0, stream>>>(x, w3, b3, w1, b1, cosb, sinb);
    pool_kernel<<<grid, block, 0, stream>>>(x, cosb, sinb, wr, br, we, be, out);
}

// Round 2
// 687.054 us; speedup vs baseline: 2.1048x; 2.1048x over previous
//
#include <hip/hip_runtime.h>
#include <math.h>

#define Bb 8
#define Cc 64
#define Hh 256
#define Ww 256
#define HID 8
#define PLANE (Hh*Ww)

// ---------------- theta kernel: LDS-tiled 3x3 conv -> 1x1 -> sigmoid*pi ----
// Block = 64x4 pixels. Tile per channel: rows [y0-1, y0+4], cols [x0-1, x0+64]
// = 6 x 66, zero-padded at image borders so conv taps are branch-free.
#define T2H 6
#define T2W 66
#define T2P 67   // padded LDS stride

__global__ __launch_bounds__(256) void theta_kernel(
    const float* __restrict__ x, const float* __restrict__ w3,
    const float* __restrict__ b3, const float* __restrict__ w1,
    const float* __restrict__ b1, float* __restrict__ cosout,
    float* __restrict__ sinout)
{
    __shared__ float tile[T2H * T2P];
    const int tid = threadIdx.x;
    const int tx = tid & 63;
    const int ty = tid >> 6;
    const int xx = blockIdx.x * 64 + tx;
    const int yy = blockIdx.y * 4 + ty;
    const int b  = blockIdx.z;
    const int row0 = blockIdx.y * 4 - 1;
    const int col0 = blockIdx.x * 64 - 1;

    const float* xb = x + (size_t)b * Cc * PLANE;

    float acc[HID];
    #pragma unroll
    for (int h = 0; h < HID; h++) acc[h] = 0.f;

    const int lbase = (ty + 1) * T2P + (tx + 1);  // local center

    for (int c = 0; c < Cc; c++) {
        const float* xc = xb + c * PLANE;
        __syncthreads();
        for (int i = tid; i < T2H * T2W; i += 256) {
            const int r  = i / T2W;
            const int cc = i - r * T2W;
            const int gy = row0 + r;
            const int gx = col0 + cc;
            float v = 0.f;
            if (gy >= 0 && gy < Hh && gx >= 0 && gx < Ww) v = xc[gy * Ww + gx];
            tile[r * T2P + cc] = v;
        }
        __syncthreads();

        float v[9];
        #pragma unroll
        for (int dy = 0; dy < 3; dy++)
            #pragma unroll
            for (int dx = 0; dx < 3; dx++)
                v[dy * 3 + dx] = tile[lbase + (dy - 1) * T2P + (dx - 1)];

        #pragma unroll
        for (int h = 0; h < HID; h++) {
            const float* wk = w3 + (h * Cc + c) * 9;  // uniform -> s_load
            float a = acc[h];
            #pragma unroll
            for (int k = 0; k < 9; k++) a = fmaf(wk[k], v[k], a);
            acc[h] = a;
        }
    }

    float z = b1[0];
    #pragma unroll
    for (int h = 0; h < HID; h++) {
        float hr = acc[h] + b3[h];
        hr = hr > 0.f ? hr : 0.f;
        z = fmaf(w1[h], hr, z);
    }
    const float theta = 3.14159265358979f / (1.f + __expf(-z));
    float s, co;
    __sincosf(theta, &s, &co);
    const int p = b * PLANE + yy * Ww + xx;
    cosout[p] = co;
    sinout[p] = s;
}

// ---------------- pool kernel: LDS-tiled oriented pooling + attention -------
// Block = 64x4 pixels. All 18 bilinear samples (9 tan + 9 nor, |t|<=4) for a
// pixel lie in [y-4, y+5] x [x-4, x+5]; the block footprint per channel is
// rows [y0-4, y0+8] x cols [x0-4, x0+69] = 13 x 74 (clamped coords stay
// inside this window, +1 bilinear neighbors included).
#define TPH 13
#define TPW 74
#define TPP 75   // padded LDS stride (odd -> breaks pow2 bank strides)

__global__ __launch_bounds__(256) void pool_kernel(
    const float* __restrict__ x,
    const float* __restrict__ cosb, const float* __restrict__ sinb,
    const float* __restrict__ wr, const float* __restrict__ br,
    const float* __restrict__ we, const float* __restrict__ be,
    float* __restrict__ out)
{
    __shared__ float tile[TPH * TPP];
    const int tid = threadIdx.x;
    const int tx = tid & 63;
    const int ty = tid >> 6;
    const int xx = blockIdx.x * 64 + tx;
    const int yy = blockIdx.y * 4 + ty;
    const int b  = blockIdx.z;
    const int p  = b * PLANE + yy * Ww + xx;
    const int row0 = blockIdx.y * 4 - 4;
    const int col0 = blockIdx.x * 64 - 4;

    const float vx = cosb[p];   // cos(theta)
    const float vy = sinb[p];   // sin(theta)

    // Precompute 18 bilinear descriptors with TILE-LOCAL offsets.
    // Clamp trick: x0=min(floor(cx),W-2), wx=cx-x0 reproduces reference edge
    // behavior exactly (at cx=W-1: x0=W-2, wx=1 selects col W-1).
    int   off[18];
    float fwy[18], fwx[18];
    #pragma unroll
    for (int s = 0; s < 9; s++) {
        const float t = (float)(s - 4);
        // tangential: cy = y + t*sin, cx = x + t*cos
        float cy = fminf(fmaxf((float)yy + t * vy, 0.f), (float)(Hh - 1));
        float cx = fminf(fmaxf((float)xx + t * vx, 0.f), (float)(Ww - 1));
        int y0 = min((int)cy, Hh - 2);
        int x0 = min((int)cx, Ww - 2);
        off[s] = (y0 - row0) * TPP + (x0 - col0);
        fwy[s] = cy - (float)y0;
        fwx[s] = cx - (float)x0;
        // normal: cy = y + t*cos, cx = x - t*sin
        float cy2 = fminf(fmaxf((float)yy + t * vx, 0.f), (float)(Hh - 1));
        float cx2 = fminf(fmaxf((float)xx - t * vy, 0.f), (float)(Ww - 1));
        int y02 = min((int)cy2, Hh - 2);
        int x02 = min((int)cx2, Ww - 2);
        off[9 + s] = (y02 - row0) * TPP + (x02 - col0);
        fwy[9 + s] = cy2 - (float)y02;
        fwx[9 + s] = cx2 - (float)x02;
    }

    float hid[HID];
    #pragma unroll
    for (int h = 0; h < HID; h++) hid[h] = br[h];

    const float* xb = x + (size_t)b * Cc * PLANE;

    for (int c = 0; c < Cc; c++) {
        const float* xc = xb + c * PLANE;
        __syncthreads();
        for (int i = tid; i < TPH * TPW; i += 256) {
            const int r  = i / TPW;
            const int cc = i - r * TPW;
            const int gy = min(max(row0 + r, 0), Hh - 1);
            const int gx = min(max(col0 + cc, 0), Ww - 1);
            tile[r * TPP + cc] = xc[gy * Ww + gx];
        }
        __syncthreads();

        float tacc = 0.f, nacc = 0.f;
        #pragma unroll
        for (int s = 0; s < 18; s++) {
            const int o = off[s];
            const float v00 = tile[o];
            const float v01 = tile[o + 1];         // ds_read2 with v00
            const float v10 = tile[o + TPP];
            const float v11 = tile[o + TPP + 1];   // ds_read2 with v10
            const float wx_ = fwx[s], wy_ = fwy[s];
            const float top = v00 + wx_ * (v01 - v00);
            const float bot = v10 + wx_ * (v11 - v10);
            const float val = top + wy_ * (bot - top);
            if (s < 9) tacc += val; else nacc += val;
        }
        tacc *= (1.f / 9.f);
        nacc *= (1.f / 9.f);
        #pragma unroll
        for (int h = 0; h < HID; h++) {
            hid[h] = fmaf(wr[h * 128 + c],      tacc, hid[h]);  // uniform
            hid[h] = fmaf(wr[h * 128 + 64 + c], nacc, hid[h]);
        }
    }

    #pragma unroll
    for (int h = 0; h < HID; h++) hid[h] = fmaxf(hid[h], 0.f);

    // Epilogue: w = sigmoid(we @ hidden + be); out = (w[c] + w[c+64]) * x[c]
    const int pix = yy * Ww + xx;
    for (int c = 0; c < Cc; c++) {
        float z1 = be[c];
        float z2 = be[c + 64];
        #pragma unroll
        for (int h = 0; h < HID; h++) {
            z1 = fmaf(we[c * 8 + h],        hid[h], z1);
            z2 = fmaf(we[(c + 64) * 8 + h], hid[h], z2);
        }
        const float a1 = 1.f / (1.f + __expf(-z1));
        const float a2 = 1.f / (1.f + __expf(-z2));
        const float xv = xb[c * PLANE + pix];
        out[(size_t)(b * Cc + c) * PLANE + pix] = (a1 + a2) * xv;
    }
}

extern "C" void kernel_launch(void* const* d_in, const int* in_sizes, int n_in,
                              void* d_out, int out_size, void* d_ws, size_t ws_size,
                              hipStream_t stream) {
    const float* x  = (const float*)d_in[0];
    const float* w3 = (const float*)d_in[1];
    const float* b3 = (const float*)d_in[2];
    const float* w1 = (const float*)d_in[3];
    const float* b1 = (const float*)d_in[4];
    const float* wr = (const float*)d_in[5];
    const float* br = (const float*)d_in[6];
    const float* we = (const float*)d_in[7];
    const float* be = (const float*)d_in[8];
    float* out = (float*)d_out;

    float* cosb = (float*)d_ws;                    // B*H*W floats
    float* sinb = cosb + (size_t)Bb * PLANE;       // B*H*W floats

    dim3 grid(Ww / 64, Hh / 4, Bb);
    dim3 block(256);
    theta_kernel<<<grid, block, 0, stream>>>(x, w3, b3, w1, b1, cosb, sinb);
    pool_kernel<<<grid, block, 0, stream>>>(x, cosb, sinb, wr, br, we, be, out);
}